// Round 11
// baseline (1608.575 us; speedup 1.0000x reference)
//
#include <hip/hip_runtime.h>
#include <math.h>

#define EPS 1e-5f
#define MODW 132   // compact mod row: [0..2]=scales (+1 pad), [4..131]=shift[0..127]

#define RG 128                 // rowgroups (B/8)
#define S1_BLKS (RG * 8)       // 1024
#define S2_BLKS (RG * 8)       // 1024
#define S3_BLKS (RG * 3)       // 384
#define NODE_BASE (S1_BLKS + S2_BLKS + S3_BLKS)   // 2432

__device__ __forceinline__ float silu_f(float x) {
    return x / (1.0f + expf(-x));
}

// ---- one MLP stage slice on 256 threads: 8 rows x 64 cols, split-k 4 ----
// k-loop in chunks of 16: 16 independent scalar w loads per batch, then
// 4x[8 LDS float4 broadcasts + 32 FMAs]. Split-k partials reduced via LDS.
template <int K, int OUTC, bool EMB, bool SILU, bool COLMAP>
__device__ __forceinline__ void stage256(
    const float* __restrict__ src,   // [*][K] rows (or t[] if EMB)
    const float* __restrict__ w,     // [K][NCW]
    int NCW,
    const float* __restrict__ bias,  // [NCW]
    float* __restrict__ dst, int dstride,
    int row0, int col0,
    float* s_in, float* s_acc, int tid)
{
    if constexpr (EMB) {
        const float lm = 9.210340371976184f;   // ln(10000)
        for (int idx = tid; idx < 8 * K; idx += 256) {
            int r = idx / K, j = idx - r * K;
            int h = j & 127;
            float freq = expf(-lm * (float)h * (1.0f / 128.0f));
            float arg = src[row0 + r] * freq;
            s_in[r * K + j] = (j < 128) ? cosf(arg) : sinf(arg);
        }
    } else {
        for (int idx = tid; idx < 8 * (K / 4); idx += 256) {
            int r = idx / (K / 4), k4 = idx - r * (K / 4);
            *(float4*)&s_in[r * K + k4 * 4] =
                *(const float4*)(src + (size_t)(row0 + r) * K + k4 * 4);
        }
    }
    __syncthreads();

    int c  = tid & 63;
    int ks = tid >> 6;                 // wave-uniform k-slice (0..3)
    constexpr int KC = K / 4;
    int oc = col0 + c;
    int occ = (oc < OUTC) ? oc : (OUTC - 1);                // clamp (never stored)
    int wcol = COLMAP ? ((occ < 4) ? occ : (220 + occ)) : occ;
    const float* wp = w + wcol;

    float acc[8] = {0, 0, 0, 0, 0, 0, 0, 0};
    int kbeg = ks * KC;
#pragma unroll 1
    for (int k0 = kbeg; k0 < kbeg + KC; k0 += 16) {
        float wv[16];
#pragma unroll
        for (int u = 0; u < 16; ++u) wv[u] = wp[(size_t)(k0 + u) * NCW];
#pragma unroll
        for (int q = 0; q < 4; ++q) {
            float4 sa[8];
#pragma unroll
            for (int r = 0; r < 8; ++r) sa[r] = *(const float4*)&s_in[r * K + k0 + 4 * q];
#pragma unroll
            for (int u = 0; u < 4; ++u)
#pragma unroll
                for (int r = 0; r < 8; ++r)
                    acc[r] += ((const float*)&sa[r])[u] * wv[4 * q + u];
        }
    }

#pragma unroll
    for (int r = 0; r < 8; ++r) s_acc[(ks * 8 + r) * 64 + c] = acc[r];
    __syncthreads();

    for (int o = tid; o < 512; o += 256) {
        int r = o >> 6, cc = o & 63;
        int jo = col0 + cc;
        if (jo < OUTC) {
            float v = s_acc[(0 * 8 + r) * 64 + cc] + s_acc[(1 * 8 + r) * 64 + cc]
                    + s_acc[(2 * 8 + r) * 64 + cc] + s_acc[(3 * 8 + r) * 64 + cc];
            int wc = COLMAP ? ((jo < 4) ? jo : (220 + jo)) : jo;
            v += bias[wc];
            if constexpr (SILU) v = silu_f(v);
            dst[(size_t)(row0 + r) * dstride + jo] = v;
        }
    }
}

__device__ __forceinline__ void flag_release(int* f, int tid) {
    __threadfence();
    __syncthreads();
    if (tid == 0) __hip_atomic_fetch_add(f, 1, __ATOMIC_RELEASE, __HIP_MEMORY_SCOPE_AGENT);
}

__device__ __forceinline__ void flag_acquire(const int* f, int target, int tid) {
    if (tid == 0) {
        while (__hip_atomic_load(f, __ATOMIC_ACQUIRE, __HIP_MEMORY_SCOPE_AGENT) < target)
            __builtin_amdgcn_s_sleep(2);
    }
    __syncthreads();
    __threadfence();
}

// One kernel: block-role specialization + flag dataflow.
//   bid <  1024        : stage1  (emb -> silu(emb@w1+b1)), sets flag1[g]
//   bid <  2048        : stage2  (silu(h1@w2+b2)), waits flag1[g]==8, sets flag2[g]
//   bid <  2432        : stage3  (h2@wm+bm, pruned 132 cols), waits flag2[g]==8, modflag++
//   bid >= 2432        : node work (one wave per node), waits modflag==384 AFTER x-load+reduce
__global__ __launch_bounds__(256) void k_all(
    const float* __restrict__ x, const float* __restrict__ t,
    const int* __restrict__ batch,
    const float* __restrict__ w1, const float* __restrict__ b1,
    const float* __restrict__ w2, const float* __restrict__ b2,
    const float* __restrict__ wm, const float* __restrict__ bm,
    float* __restrict__ out, int N,
    int* __restrict__ flags,      // [0..127]=f1, [128..255]=f2, [256]=modflag
    float* __restrict__ h1, float* __restrict__ h2, float* __restrict__ mb)
{
    __shared__ __align__(16) float s_in[8 * 512];     // 16 KB
    __shared__ __align__(16) float s_acc[4 * 8 * 64]; // 8 KB
    int bid = blockIdx.x;
    int tid = threadIdx.x;

    if (bid < S1_BLKS) {
        int g = bid >> 3, cg = bid & 7;
        stage256<256, 512, true, true, false>(t, w1, 512, b1, h1, 512,
                                              g * 8, cg * 64, s_in, s_acc, tid);
        flag_release(&flags[g], tid);
        return;
    }
    if (bid < S1_BLKS + S2_BLKS) {
        int lb = bid - S1_BLKS;
        int g = lb >> 3, cg = lb & 7;
        flag_acquire(&flags[g], 8, tid);
        stage256<512, 512, false, true, false>(h1, w2, 512, b2, h2, 512,
                                               g * 8, cg * 64, s_in, s_acc, tid);
        flag_release(&flags[128 + g], tid);
        return;
    }
    if (bid < NODE_BASE) {
        int lb = bid - (S1_BLKS + S2_BLKS);
        int g = lb / 3, cg = lb - g * 3;
        flag_acquire(&flags[128 + g], 8, tid);
        stage256<512, MODW, false, false, true>(h2, wm, 352, bm, mb, MODW,
                                                g * 8, cg * 64, s_in, s_acc, tid);
        flag_release(&flags[256], tid);
        return;
    }

    // ---- node work: one wave per node; row = 480 f32 = 120 float4 ----
    int node = (bid - NODE_BASE) * 4 + (tid >> 6);
    if (node >= N) return;
    int lane = tid & 63;

    const float4* rp = (const float4*)(x + (size_t)node * 480);
    float4 a = rp[lane];                          // f4 idx 0..63
    float4 c = make_float4(0.f, 0.f, 0.f, 0.f);
    if (lane < 56) c = rp[64 + lane];             // f4 idx 64..119

    float s0 = 0.f, q0 = 0.f, q1 = 0.f, q2 = 0.f;
    float da = a.x * a.x + a.y * a.y + a.z * a.z + a.w * a.w;
    if (lane < 32) { s0 = a.x + a.y + a.z + a.w; q0 = da; }
    else           { q1 = da; }
    float dc = c.x * c.x + c.y * c.y + c.z * c.z + c.w * c.w;
    if (lane < 16)      q1 += dc;
    else if (lane < 56) q2 = dc;

#pragma unroll
    for (int m = 1; m < 64; m <<= 1) {
        s0 += __shfl_xor(s0, m, 64);
        q0 += __shfl_xor(q0, m, 64);
        q1 += __shfl_xor(q1, m, 64);
        q2 += __shfl_xor(q2, m, 64);
    }

    int b = batch[node];

    // wait for mod table (usually already done by the time streaming blocks run)
    while (__hip_atomic_load(&flags[256], __ATOMIC_ACQUIRE, __HIP_MEMORY_SCOPE_AGENT) < S3_BLKS)
        __builtin_amdgcn_s_sleep(2);

    const float* mrow = mb + (size_t)b * MODW;
    float4 m4 = *(const float4*)mrow;             // scales 0..2 (+pad)

    float mean = s0 * (1.0f / 128.0f);
    float var  = q0 * (1.0f / 128.0f) - mean * mean;
    float r0 = rsqrtf(var + EPS) * (1.0f + m4.x);
    float r1 = rsqrtf(q1 * (1.0f / 192.0f) + EPS) * (1.0f + m4.y);
    float r2 = rsqrtf(q2 * (1.0f / 160.0f) + EPS) * (1.0f + m4.z);

    float4* op = (float4*)(out + (size_t)node * 480);
    float4 o;
    if (lane < 32) {
        float4 sh = *(const float4*)(mrow + 4 + 4 * lane);   // shifts, 16B aligned
        o.x = (a.x - mean) * r0 + sh.x;
        o.y = (a.y - mean) * r0 + sh.y;
        o.z = (a.z - mean) * r0 + sh.z;
        o.w = (a.w - mean) * r0 + sh.w;
    } else {
        o.x = a.x * r1; o.y = a.y * r1; o.z = a.z * r1; o.w = a.w * r1;
    }
    op[lane] = o;
    if (lane < 56) {
        float rr = (lane < 16) ? r1 : r2;
        float4 o2;
        o2.x = c.x * rr; o2.y = c.y * rr; o2.z = c.z * rr; o2.w = c.w * rr;
        op[64 + lane] = o2;
    }
}

extern "C" void kernel_launch(void* const* d_in, const int* in_sizes, int n_in,
                              void* d_out, int out_size, void* d_ws, size_t ws_size,
                              hipStream_t stream) {
    const float* node_input = (const float*)d_in[0];
    const float* t          = (const float*)d_in[1];
    const int*   batch      = (const int*)d_in[2];
    const float* w1         = (const float*)d_in[3];
    const float* b1         = (const float*)d_in[4];
    const float* w2         = (const float*)d_in[5];
    const float* b2         = (const float*)d_in[6];
    const float* wm         = (const float*)d_in[7];
    const float* bm         = (const float*)d_in[8];
    float* out = (float*)d_out;

    int N = in_sizes[0] / 480;   // 100000
    // B = in_sizes[1] = 1024 (RG=128 rowgroups hard-coded to match)

    float* ws = (float*)d_ws;
    int*   flags = (int*)ws;                       // 257 ints (pad to 1024 floats)
    float* h1 = ws + 1024;                         // 1024*512
    float* h2 = h1 + (size_t)1024 * 512;           // 1024*512
    float* mb = h2 + (size_t)1024 * 512;           // 1024*132

    hipMemsetAsync(flags, 0, 4096, stream);

    int node_blocks = (N + 3) / 4;
    k_all<<<NODE_BASE + node_blocks, 256, 0, stream>>>(
        node_input, t, batch, w1, b1, w2, b2, wm, bm,
        out, N, flags, h1, h2, mb);
}

// Round 12
// 132.929 us; speedup vs baseline: 12.1010x; 12.1010x over previous
//
#include <hip/hip_runtime.h>
#include <math.h>

#define EPS 1e-5f
#define MODW 132   // compact mod row: [0..2]=scales (+1 pad), [4..131]=shift[0..127]
#define R 4        // rows per block

__device__ __forceinline__ float silu_f(float x) {
    return x / (1.0f + expf(-x));
}

// One 64-col tile of one MLP stage (R9's proven structure on 512 threads):
// 64 cols x KS=8 k-slices; k-loop in chunks of 16 batched scalar w loads +
// LDS float4 broadcasts; split-k partials reduced via s_acc.
// Writes to LDS (stride 512) or, if GL, to global row block (stride MODW).
template <int K, int OUTC, bool SILU, bool COLMAP, bool GL>
__device__ __forceinline__ void tile64(
    const float* s_in,               // [R][K] in LDS
    const float* __restrict__ w,     // [K][NCW]
    int NCW,
    const float* __restrict__ bias,  // [NCW]
    float* dst,                      // LDS [R][512] or global [R][MODW]
    int col0, float* s_acc, int tid)
{
    constexpr int KC = K / 8;
    int c  = tid & 63;
    int ks = tid >> 6;                         // wave-uniform k-slice
    int oc = col0 + c;
    int occ = (oc < OUTC) ? oc : (OUTC - 1);   // clamp (garbage, never stored)
    int wcol = COLMAP ? ((occ < 4) ? occ : (220 + occ)) : occ;
    const float* wp = w + wcol;

    float acc[R] = {0.f, 0.f, 0.f, 0.f};
    int kbeg = ks * KC;
#pragma unroll 1
    for (int k0 = kbeg; k0 < kbeg + KC; k0 += 16) {
        float wv[16];
#pragma unroll
        for (int u = 0; u < 16; ++u) wv[u] = wp[(size_t)(k0 + u) * NCW];
#pragma unroll
        for (int q = 0; q < 4; ++q) {
            float4 sa[R];
#pragma unroll
            for (int r = 0; r < R; ++r) sa[r] = *(const float4*)&s_in[r * K + k0 + 4 * q];
#pragma unroll
            for (int u = 0; u < 4; ++u)
#pragma unroll
                for (int r = 0; r < R; ++r)
                    acc[r] += ((const float*)&sa[r])[u] * wv[4 * q + u];
        }
    }

#pragma unroll
    for (int r = 0; r < R; ++r) s_acc[(ks * R + r) * 64 + c] = acc[r];
    __syncthreads();

    if (tid < R * 64) {
        int r  = tid >> 6;
        int cc = tid & 63;
        int jo = col0 + cc;
        if (jo < OUTC) {
            float v = 0.f;
#pragma unroll
            for (int s = 0; s < 8; ++s) v += s_acc[(s * R + r) * 64 + cc];
            int wc = COLMAP ? ((jo < 4) ? jo : (220 + jo)) : jo;
            v += bias[wc];
            if (SILU) v = silu_f(v);
            if (GL) dst[(size_t)r * MODW + jo];
            if (GL) dst[(size_t)r * MODW + jo] = v;
            else    dst[r * 512 + jo] = v;
        }
    }
    __syncthreads();   // s_acc free for next tile; dst visible
}

// Fused MLP, barrier-only (no cross-block sync): one block per 4-row group.
// emb(trig) -> silu(.@w1+b1) -> silu(.@w2+b2) -> pruned(.@wm+bm) -> mb[4][132]
__global__ __launch_bounds__(512) void k_mlp(
    const float* __restrict__ t,
    const float* __restrict__ w1, const float* __restrict__ b1,
    const float* __restrict__ w2, const float* __restrict__ b2,
    const float* __restrict__ wm, const float* __restrict__ bm,
    float* __restrict__ mb)
{
    __shared__ __align__(16) float s_a[R * 512];       // 8 KB
    __shared__ __align__(16) float s_b[R * 512];       // 8 KB
    __shared__ __align__(16) float s_acc[8 * R * 64];  // 8 KB
    int tid = threadIdx.x;
    int row0 = blockIdx.x * R;

    // timestep embedding into s_a (row stride 256 = K of stage 1)
    const float lm = 9.210340371976184f;   // ln(10000)
    for (int idx = tid; idx < R * 256; idx += 512) {
        int r = idx >> 8, j = idx & 255;
        int h = j & 127;
        float freq = expf(-lm * (float)h * (1.0f / 128.0f));
        float arg = t[row0 + r] * freq;
        s_a[r * 256 + j] = (j < 128) ? cosf(arg) : sinf(arg);
    }
    __syncthreads();

    // stage 1: s_a(emb, K=256) @ w1 + b1 -> silu -> s_b (512 cols, 8 tiles)
#pragma unroll 1
    for (int ct = 0; ct < 8; ++ct)
        tile64<256, 512, true, false, false>(s_a, w1, 512, b1, s_b, ct * 64, s_acc, tid);

    // stage 2: s_b @ w2 + b2 -> silu (folded trailing silu) -> s_a (8 tiles)
#pragma unroll 1
    for (int ct = 0; ct < 8; ++ct)
        tile64<512, 512, true, false, false>(s_b, w2, 512, b2, s_a, ct * 64, s_acc, tid);

    // stage 3: s_a @ wm + bm, pruned cols {0..3} U [224,352) -> mb[row0..][132] (3 tiles)
    float* mrow = mb + (size_t)row0 * MODW;
#pragma unroll 1
    for (int ct = 0; ct < 3; ++ct)
        tile64<512, MODW, false, true, true>(s_a, wm, 352, bm, mrow, ct * 64, s_acc, tid);
}

// One wave (64 lanes) per node. Row = 480 f32 = 120 float4.
// float4 idx:  0..31 -> seg0 (layernorm, floats 0..127)
//             32..79 -> seg1 (floats 128..319, 192 elems)
//             80..119-> seg2 (floats 320..479, 160 elems)
// mod row is compact MODW=132: [0..2] scales, [4+i] = shift[i] (i<128).
__global__ __launch_bounds__(256) void k_main(const float* __restrict__ x,
                                              const int* __restrict__ batch,
                                              const float* __restrict__ mod,
                                              float* __restrict__ out, int N) {
    int node = blockIdx.x * 4 + (threadIdx.x >> 6);
    if (node >= N) return;
    int lane = threadIdx.x & 63;

    const float4* rp = (const float4*)(x + (size_t)node * 480);
    float4 a = rp[lane];                         // f4 idx lane (0..63)
    float4 c = make_float4(0.f, 0.f, 0.f, 0.f);
    if (lane < 56) c = rp[64 + lane];            // f4 idx 64..119

    float s0 = 0.f, q0 = 0.f, q1 = 0.f, q2 = 0.f;
    float da = a.x * a.x + a.y * a.y + a.z * a.z + a.w * a.w;
    if (lane < 32) { s0 = a.x + a.y + a.z + a.w; q0 = da; }
    else           { q1 = da; }
    float dc = c.x * c.x + c.y * c.y + c.z * c.z + c.w * c.w;
    if (lane < 16)      q1 += dc;
    else if (lane < 56) q2 = dc;

#pragma unroll
    for (int m = 1; m < 64; m <<= 1) {
        s0 += __shfl_xor(s0, m, 64);
        q0 += __shfl_xor(q0, m, 64);
        q1 += __shfl_xor(q1, m, 64);
        q2 += __shfl_xor(q2, m, 64);
    }

    int b = batch[node];
    const float* mrow = mod + (size_t)b * MODW;
    float4 m4 = *(const float4*)mrow;            // scales 0..2 (+pad)

    float mean = s0 * (1.0f / 128.0f);
    float var  = q0 * (1.0f / 128.0f) - mean * mean;
    float r0 = rsqrtf(var + EPS) * (1.0f + m4.x);
    float r1 = rsqrtf(q1 * (1.0f / 192.0f) + EPS) * (1.0f + m4.y);
    float r2 = rsqrtf(q2 * (1.0f / 160.0f) + EPS) * (1.0f + m4.z);

    float4* op = (float4*)(out + (size_t)node * 480);
    float4 o;
    if (lane < 32) {
        float4 sh = *(const float4*)(mrow + 4 + 4 * lane);   // shifts, 16B aligned
        o.x = (a.x - mean) * r0 + sh.x;
        o.y = (a.y - mean) * r0 + sh.y;
        o.z = (a.z - mean) * r0 + sh.z;
        o.w = (a.w - mean) * r0 + sh.w;
    } else {
        o.x = a.x * r1; o.y = a.y * r1; o.z = a.z * r1; o.w = a.w * r1;
    }
    op[lane] = o;
    if (lane < 56) {
        float rr = (lane < 16) ? r1 : r2;
        float4 o2;
        o2.x = c.x * rr; o2.y = c.y * rr; o2.z = c.z * rr; o2.w = c.w * rr;
        op[64 + lane] = o2;
    }
}

extern "C" void kernel_launch(void* const* d_in, const int* in_sizes, int n_in,
                              void* d_out, int out_size, void* d_ws, size_t ws_size,
                              hipStream_t stream) {
    const float* node_input = (const float*)d_in[0];
    const float* t          = (const float*)d_in[1];
    const int*   batch      = (const int*)d_in[2];
    const float* w1         = (const float*)d_in[3];
    const float* b1         = (const float*)d_in[4];
    const float* w2         = (const float*)d_in[5];
    const float* b2         = (const float*)d_in[6];
    const float* wm         = (const float*)d_in[7];
    const float* bm         = (const float*)d_in[8];
    float* out = (float*)d_out;

    int N = in_sizes[0] / 480;   // 100000
    int B = in_sizes[1];         // 1024

    float* mb = (float*)d_ws;    // B*132 compact mod

    k_mlp<<<B / R, 512, 0, stream>>>(t, w1, b1, w2, b2, wm, bm, mb);
    k_main<<<(N + 3) / 4, 256, 0, stream>>>(node_input, batch, mb, out, N);
}